// Round 10
// baseline (1245.981 us; speedup 1.0000x reference)
//
#include <hip/hip_runtime.h>

#define NB 16
#define NP 2048
#define NR 64
#define NS 64
#define KSEL 40

typedef __attribute__((ext_vector_type(8))) short bf16x8;
typedef __attribute__((ext_vector_type(4))) float f32x4;

// ------------------------- static scratch arenas -------------------------
constexpr long aOUT1 = 0;
constexpr long aT1A  = aOUT1 + 16L*2048*128;
constexpr long aT2A  = aT1A  + 16L*2048*6;
constexpr long aZ1   = aT2A  + 16L*2048*6;
constexpr long aVALS1= aZ1   + 16L*2048*128;
constexpr long aDIS1 = aVALS1+ 16L*2048*64;
constexpr long aVALS2= aDIS1 + 16L*2048;
constexpr long aDIS2 = aVALS2+ 16L*2048*64;
constexpr long aXX2  = aDIS2 + 16L*2048;
constexpr long aXX1  = aXX2  + 16L*2048;
constexpr long aT1B  = aXX1  + 16L*2048;
constexpr long aT2B  = aT1B  + 16L*2048*128;
constexpr long aOUT2 = aT2B  + 16L*2048*128;
constexpr long aZ2   = aOUT2 + 16L*2048*512;
constexpr long aVFR  = aZ2   + 16L*2048*512;
constexpr long aT1R  = aVFR  + 16L*64*128;
constexpr long aT2R  = aT1R  + 16L*64*128;
constexpr long aOUTR = aT2R  + 16L*64*128;
constexpr long aZR   = aOUTR + 16L*64*512;
constexpr long aPOOL = aZR   + 16L*64*512;
constexpr long aFC1O = aPOOL + 16L*1024;
constexpr long aFC2O = aFC1O + 16L*512;
constexpr long aMPP  = aFC2O + 16L*128;
constexpr long aM1P  = aMPP  + 16L*8*512;
constexpr long aM2P  = aM1P  + 8L*16*128*128;
constexpr long FTOT  = aM2P  + 4L*16*512*512;

constexpr long iCOLS1 = 0;
constexpr long iCNT1  = iCOLS1 + 16L*2048*64;
constexpr long iCOLS2 = iCNT1  + 16L*2048;
constexpr long iCNT2  = iCOLS2 + 16L*2048*64;
constexpr long ITOT   = iCNT2  + 16L*2048;

// bf16 (ushort) arena
constexpr long uOUT1H = 0;
constexpr long uOUT1L = uOUT1H + 16L*2048*128;
constexpr long uOUT1R = uOUT1L + 16L*2048*128;
constexpr long uT1BH  = uOUT1R + 16L*2048*128;
constexpr long uT1BL  = uT1BH  + 16L*2048*128;
constexpr long uT2BH  = uT1BL  + 16L*2048*128;
constexpr long uT2BL  = uT2BH  + 16L*2048*128;
constexpr long uW2T   = uT2BL  + 16L*2048*128;
constexpr long uVFRH  = uW2T   + 512L*384;
constexpr long uVFRL  = uVFRH  + 16L*64*128;
constexpr long uT1RH  = uVFRL  + 16L*64*128;
constexpr long uT1RL  = uT1RH  + 16L*64*128;
constexpr long uT2RH  = uT1RL  + 16L*64*128;
constexpr long uT2RL  = uT2RH  + 16L*64*128;
constexpr long uWRT   = uT2RL  + 16L*64*128;
constexpr long uOUT1T = uWRT   + 512L*384;
constexpr long uZ1T   = uOUT1T + 16L*128*2048;
constexpr long uOUT2T = uZ1T   + 16L*128*2048;
constexpr long uZ2T   = uOUT2T + 16L*512*2048;
constexpr long uOUTRT = uZ2T   + 16L*512*2048;
constexpr long uZRT   = uOUTRT + 16L*512*64;
constexpr long uOUT2B = uZRT   + 16L*512*64;
constexpr long uG     = uOUT2B + 16L*2048*512;
constexpr long UTOT   = uG     + 16L*2048*2048;

__device__ __align__(256) float  g_farena[FTOT];
__device__ __align__(256) int    g_iarena[ITOT];
__device__ __align__(256) ushort g_uarena[UTOT];

// ------------------------- helpers -------------------------
__device__ __forceinline__ float wsum_f(float v){
  #pragma unroll
  for (int s=32;s>0;s>>=1) v += __shfl_xor(v, s, 64);
  return v;
}
__device__ __forceinline__ int wsum_i(int v){
  #pragma unroll
  for (int s=32;s>0;s>>=1) v += __shfl_xor(v, s, 64);
  return v;
}

__device__ __forceinline__ void gl2lds16(const void* g, void* l){
  __builtin_amdgcn_global_load_lds(
      (const __attribute__((address_space(1))) void*)g,
      (__attribute__((address_space(3))) void*)l, 16, 0, 0);
}

__device__ __forceinline__ ushort bf_rne(float x){
  unsigned u = __float_as_uint(x);
  u += 0x7fffu + ((u >> 16) & 1u);
  return (ushort)(u >> 16);
}
__device__ __forceinline__ void bf_hilo(float x, ushort& h, ushort& l){
  unsigned u = __float_as_uint(x);
  h = (ushort)(u >> 16);
  float hf = __uint_as_float(u & 0xffff0000u);
  l = (ushort)(__float_as_uint(x - hf) >> 16);
}
__device__ __forceinline__ float bf2f(ushort u){
  return __uint_as_float(((unsigned)u) << 16);
}

// ------------------------- top-k machinery -------------------------
// KSEL-smallest selection over 2048 POSITIVE dist floats (32/lane).
__device__ __forceinline__ void topk_store(float (&dk)[32], int lane, long row,
    int* __restrict__ cols, float* __restrict__ vals,
    int* __restrict__ cnt, float* __restrict__ dis)
{
  float dmin = dk[0], dmax = dk[0];
  #pragma unroll
  for (int q=1;q<32;++q){ dmin = fminf(dmin, dk[q]); dmax = fmaxf(dmax, dk[q]); }
  #pragma unroll
  for (int s=32;s>0;s>>=1){
    dmin = fminf(dmin, __shfl_xor(dmin, s, 64));
    dmax = fmaxf(dmax, __shfl_xor(dmax, s, 64));
  }
  int c0 = 0;
  #pragma unroll
  for (int q=0;q<32;++q) c0 += (int)__popcll(__ballot(dk[q] <= dmin));
  float kth;
  if (c0 >= KSEL){
    kth = dmin;
  } else {
    float lo = dmin, hi = dmax;
    int cLo = c0, cHi = 2048, it = 0;
    while (cHi != KSEL && __float_as_uint(hi) - __float_as_uint(lo) > 1u){
      float t;
      if (it & 1){
        t = __uint_as_float((__float_as_uint(lo) + __float_as_uint(hi)) >> 1);
      } else {
        t = lo + (hi - lo) * ((float)(KSEL - cLo) / (float)(cHi - cLo));
        unsigned tb = __float_as_uint(t);
        unsigned lb = __float_as_uint(lo), hb = __float_as_uint(hi);
        if (tb <= lb) tb = lb + 1u;
        else if (tb >= hb) tb = hb - 1u;
        t = __uint_as_float(tb);
      }
      ++it;
      int c = 0;
      #pragma unroll
      for (int q=0;q<32;++q) c += (int)__popcll(__ballot(dk[q] <= t));
      if (c >= KSEL){ hi = t; cHi = c; } else { lo = t; cLo = c; }
    }
    kth = hi;
  }
  int kc = 0;
  #pragma unroll
  for (int q=0;q<32;++q) kc += (dk[q] <= kth) ? 1 : 0;
  int tot = wsum_i(kc);
  int incl = kc;
  #pragma unroll
  for (int s=1;s<64;s<<=1){ int u = __shfl_up(incl, s, 64); if (lane >= s) incl += u; }
  int pos = incl - kc;
  int* cp = cols + row*64; float* vp = vals + row*64;
  float d = 0.f;
  #pragma unroll
  for (int q=0;q<32;++q){
    if (dk[q] <= kth){
      float v = __expf(-dk[q]);
      d += v;
      if (pos < 64){ cp[pos] = q*64 + lane; vp[pos] = v; }
      pos++;
    }
  }
  d = wsum_f(d);
  if (lane == 0){
    cnt[row] = tot <= 64 ? tot : 64;
    dis[row] = d > 0.f ? (1.0f / sqrtf(fmaxf(d, 1e-12f))) : 0.f;
  }
}

__global__ __launch_bounds__(256) void xx6_kernel(const float* __restrict__ x,
    float* __restrict__ xx1)
{
  long i = (long)blockIdx.x*256 + threadIdx.x;
  const float* p = x + i*6;
  float2 v0 = *(const float2*)(p);
  float2 v1 = *(const float2*)(p+2);
  float2 v2 = *(const float2*)(p+4);
  xx1[i] = v0.x*v0.x + v0.y*v0.y + v1.x*v1.x + v1.y*v1.y + v2.x*v2.x + v2.y*v2.y;
}

__global__ __launch_bounds__(256) void knn1_kernel(const float* __restrict__ x,
    const float* __restrict__ xx1,
    int* __restrict__ cols, float* __restrict__ vals, int* __restrict__ cnt,
    float* __restrict__ dis)
{
  int lane = threadIdx.x & 63;
  long row = (long)blockIdx.x*4 + (threadIdx.x >> 6);
  int b = (int)(row >> 11); int i = (int)(row & (NP-1));
  const float* xb = x + (long)b*NP*6;
  const float* xxb = xx1 + ((long)b << 11);
  float xi[6];
  #pragma unroll
  for (int d2=0; d2<6; ++d2) xi[d2] = xb[(long)i*6 + d2];
  float xxi = xxb[i];
  float dk[32];
  #pragma unroll 4
  for (int c=0;c<32;++c){
    int j = c*64 + lane;
    const float* xj = xb + (long)j*6;
    float2 v0 = *(const float2*)(xj);
    float2 v1 = *(const float2*)(xj+2);
    float2 v2 = *(const float2*)(xj+4);
    float inr = xi[0]*v0.x + xi[1]*v0.y + xi[2]*v1.x + xi[3]*v1.y + xi[4]*v2.x + xi[5]*v2.y;
    dk[c] = fmaxf(xxi + xxb[j] - 2.f*inr, 0.f);
  }
  topk_store(dk, lane, row, cols, vals, cnt, dis);
}

// one launch over all 32768 rows; G is bf16 [16][2048][2048] (L3-resident)
__global__ __launch_bounds__(256) void knn2_kernel(const ushort* __restrict__ G,
    const float* __restrict__ xx,
    int* __restrict__ cols, float* __restrict__ vals, int* __restrict__ cnt,
    float* __restrict__ dis)
{
  int lane = threadIdx.x & 63;
  long row = (long)blockIdx.x*4 + (threadIdx.x >> 6);
  const ushort* Gr = G + row*NP;
  const float* xxb = xx + ((row >> 11) << 11);
  int i = (int)(row & (NP-1));
  float xxi = xxb[i];
  float dk[32];
  #pragma unroll 4
  for (int c=0;c<32;++c){
    int j = c*64 + lane;
    dk[c] = fmaxf(xxi + xxb[j] - 2.f*bf2f(Gr[j]), 0.f);
  }
  topk_store(dk, lane, row, cols, vals, cnt, dis);
}

// ------------------------- sparse L application -------------------------
__global__ __launch_bounds__(256) void spmm6_kernel(const float* __restrict__ X,
    const float* __restrict__ T0, float* __restrict__ Y,
    const int* __restrict__ cols, const float* __restrict__ vals,
    const int* __restrict__ cnt, const float* __restrict__ dis,
    float c1, float c2, float cs)
{
  long row = (long)blockIdx.x*256 + threadIdx.x;
  int b = (int)(row >> 11);
  const float* Xb = X + ((long)b << 11)*6;
  const float* db = dis + ((long)b << 11);
  float acc[6] = {0,0,0,0,0,0};
  int c = cnt[row];
  const int* cp = cols + row*64; const float* vp = vals + row*64;
  for (int t=0;t<c;++t){
    int j = cp[t];
    float w = vp[t] * db[j];
    const float* xr = Xb + (long)j*6;
    #pragma unroll
    for (int d2=0; d2<6; ++d2) acc[d2] += w * xr[d2];
  }
  float di = dis[row];
  #pragma unroll
  for (int d2=0; d2<6; ++d2)
    Y[row*6+d2] = c1*X[row*6+d2] + c2*T0[row*6+d2] - cs*di*acc[d2];
}

// XCD-swizzled; optionally emits trunc hi/lo bf16 pair of the result.
template<int W, bool PACK>
__global__ __launch_bounds__((W >= 256) ? 256 : W) void spmm_kernel(
    const float* __restrict__ X, const float* __restrict__ T0, float* __restrict__ Y,
    ushort* __restrict__ Hh, ushort* __restrict__ Ll,
    const int* __restrict__ cols, const float* __restrict__ vals,
    const int* __restrict__ cnt, const float* __restrict__ dis,
    float c1, float c2, float cs)
{
  constexpr int TPB = (W >= 256) ? 256 : W;
  constexpr int E = W / TPB;
  __shared__ int scol[64];
  __shared__ float sval[64];
  int q = blockIdx.x;
  long row = ((long)(q & 7) << 12) + (q >> 3);
  int b = (int)(row >> 11);
  int tid = threadIdx.x;
  int c = cnt[row];
  if (tid < 64){ scol[tid] = cols[row*64+tid]; sval[tid] = vals[row*64+tid]; }
  __syncthreads();
  const float* Xb = X + ((long)b << 11)*W;
  const float* db = dis + ((long)b << 11);
  float acc[E] = {};
  for (int t=0;t<c;++t){
    int j = scol[t];
    float w = sval[t] * db[j];
    const float* xr = Xb + (long)j*W;
    #pragma unroll
    for (int e=0;e<E;++e) acc[e] += w * xr[tid + e*TPB];
  }
  float di = dis[row];
  #pragma unroll
  for (int e=0;e<E;++e){
    long idx = row*W + tid + e*TPB;
    float y = c1*X[idx] + c2*T0[idx] - cs*di*acc[e];
    Y[idx] = y;
    if (PACK){
      ushort h, l; bf_hilo(y, h, l);
      Hh[idx] = h; Ll[idx] = l;
    }
  }
}

// Z = X - diag(dis) S X with bf16 gather source (reg-norm path only).
__global__ __launch_bounds__(256) void spmmb_kernel(
    const float* __restrict__ X, const ushort* __restrict__ Xb,
    float* __restrict__ Y,
    const int* __restrict__ cols, const float* __restrict__ vals,
    const int* __restrict__ cnt, const float* __restrict__ dis)
{
  __shared__ int scol[4][64];
  __shared__ float sval[4][64];
  int q = blockIdx.x;
  int wid = threadIdx.x >> 6, lane = threadIdx.x & 63;
  long row = ((long)(q & 7) << 12) + ((long)(q >> 3) << 2) + wid;
  int b = (int)(row >> 11);
  scol[wid][lane] = cols[row*64 + lane];
  sval[wid][lane] = vals[row*64 + lane];
  const ushort* Xbb = Xb + ((long)b << 11)*512;
  const float* db = dis + ((long)b << 11);
  int c = cnt[row];
  float acc[8] = {};
  for (int t=0;t<c;++t){
    int j = scol[wid][t];
    float w = sval[wid][t] * db[j];
    bf16x8 v = *(const bf16x8*)(Xbb + (long)j*512 + lane*8);
    #pragma unroll
    for (int e=0;e<8;++e)
      acc[e] += w * bf2f((ushort)v[e]);
  }
  float di = dis[row];
  long base = row*512 + lane*8;
  float4 x0 = *(const float4*)(X + base);
  float4 x1 = *(const float4*)(X + base + 4);
  float4 o0, o1;
  o0.x = x0.x - di*acc[0]; o0.y = x0.y - di*acc[1];
  o0.z = x0.z - di*acc[2]; o0.w = x0.w - di*acc[3];
  o1.x = x1.x - di*acc[4]; o1.y = x1.y - di*acc[5];
  o1.z = x1.z - di*acc[6]; o1.w = x1.w - di*acc[7];
  *(float4*)(Y + base) = o0;
  *(float4*)(Y + base + 4) = o1;
}

// ------------------------- conv1 (K=18, direct; fused bf16 packs) --------
__global__ __launch_bounds__(128) void conv1_kernel(const float* __restrict__ x,
    const float* __restrict__ t1, const float* __restrict__ t2,
    const float* __restrict__ w, const float* __restrict__ bias,
    float* __restrict__ out, ushort* __restrict__ oh, ushort* __restrict__ ol,
    ushort* __restrict__ orr)
{
  long row = blockIdx.x; int o = threadIdx.x;
  float acc = bias[o];
  const float* xr = x + row*6; const float* a1 = t1 + row*6; const float* a2 = t2 + row*6;
  #pragma unroll
  for (int d2=0; d2<6; ++d2){
    acc += xr[d2]*w[d2*128 + o];
    acc += a1[d2]*w[(6+d2)*128 + o];
    acc += a2[d2]*w[(12+d2)*128 + o];
  }
  acc = fmaxf(acc, 0.f);
  long idx = row*128 + o;
  out[idx] = acc;
  ushort h, l; bf_hilo(acc, h, l);
  oh[idx] = h; ol[idx] = l;
  orr[idx] = bf_rne(acc);
}

// transpose fp32 [R][C] -> bf16 [C][R]; HILO: trunc hi/lo pair, else RNE
template<bool HILO>
__global__ __launch_bounds__(256) void tpack_kernel(const float* __restrict__ X,
    ushort* __restrict__ H, ushort* __restrict__ L,
    int R, int C, long sIn, long sOut)
{
  __shared__ float tile[32][33];
  int c0 = blockIdx.x*32, r0 = blockIdx.y*32, b = blockIdx.z;
  const float* Xb = X + (long)b*sIn;
  int tx = threadIdx.x & 31, ty = threadIdx.x >> 5;
  #pragma unroll
  for (int rr=ty; rr<32; rr+=8)
    tile[rr][tx] = Xb[(long)(r0+rr)*C + c0+tx];
  __syncthreads();
  #pragma unroll
  for (int cc=ty; cc<32; cc+=8){
    float xv = tile[tx][cc];
    long oidx = (long)b*sOut + (long)(c0+cc)*R + r0 + tx;
    if (HILO){
      ushort h, l; bf_hilo(xv, h, l);
      H[oidx] = h; L[oidx] = l;
    } else {
      H[oidx] = bf_rne(xv);
    }
  }
}

// ------------------------- bf16 MFMA GEMM (global_load_lds + swizzle) ----
// C[m][n] = sum_k A[m][k]*B[n][k]. SPLITA: A=Ah+Al (2 MFMA, B single).
// C (fp32) and Cb (bf16) stores both optional. ssq: atomicAdd ||C||^2 only.
// kchunk>0: split-K — blockIdx.z = split*16 + batch, K range [split*kchunk,+kchunk),
// C partial slab at C + split*sSplit.
template<bool SPLITA, bool CHEB, bool BR>
__global__ __launch_bounds__(256) void mgemm_kernel(
    const ushort* __restrict__ Ah0, const ushort* __restrict__ Ah1, const ushort* __restrict__ Ah2,
    const ushort* __restrict__ Al0, const ushort* __restrict__ Al1, const ushort* __restrict__ Al2,
    const ushort* __restrict__ Bh,
    const float* __restrict__ bias, float* __restrict__ C,
    ushort* __restrict__ Cb, float* __restrict__ ssq,
    int M, int N, int K, long sA, long sB, long sC,
    int kchunk, long sSplit)
{
  __shared__ ushort AsH[128*32];
  __shared__ ushort BsH[128*32];
  __shared__ ushort AsL[SPLITA ? 128*32 : 8];
  int bz = blockIdx.z;
  int kb = 0, ke = K;
  long coff = 0;
  if (kchunk > 0){
    int split = bz >> 4; bz &= 15;
    kb = split * kchunk;
    ke = kb + kchunk; if (ke > K) ke = K;
    coff = (long)split * sSplit;
  }
  int m0 = blockIdx.x*128, n0 = blockIdx.y*128;
  int tid = threadIdx.x, lane = tid & 63, wid = tid >> 6;
  int wm = (wid & 1)*64, wn = (wid >> 1)*64;
  f32x4 acc[4][4] = {};
  const ushort* Bb = Bh + (long)bz*sB;
  const ushort* Ab = CHEB ? Ah0 : (Ah0 + (long)bz*sA);
  const ushort* Alb = (SPLITA && !CHEB) ? (Al0 + (long)bz*sA) : Al0;

  for (int k0 = kb; k0 < ke; k0 += 32){
    #pragma unroll
    for (int cc2=0; cc2<2; ++cc2){
      int chunk = wid*2 + cc2;
      int e = chunk*512 + lane*8;
      int row = e >> 5;
      int slot = (e >> 3) & 3;
      int scol = (slot ^ ((row >> 1) & 3)) * 8;
      const ushort* asrc;
      if (CHEB){
        int kg2 = k0 + scol;
        const ushort* base = (kg2 < 128) ? Ah0 : ((kg2 < 256) ? Ah1 : Ah2);
        asrc = base + (long)(m0+row)*128 + (kg2 & 127);
      } else {
        asrc = Ab + (long)(m0+row)*K + k0 + scol;
      }
      gl2lds16(asrc, &AsH[chunk*512]);
      gl2lds16(Bb + (long)(n0+row)*K + k0 + scol, &BsH[chunk*512]);
      if (SPLITA){
        const ushort* alsrc;
        if (CHEB){
          int kg2 = k0 + scol;
          const ushort* base = (kg2 < 128) ? Al0 : ((kg2 < 256) ? Al1 : Al2);
          alsrc = base + (long)(m0+row)*128 + (kg2 & 127);
        } else {
          alsrc = Alb + (long)(m0+row)*K + k0 + scol;
        }
        gl2lds16(alsrc, &AsL[chunk*512]);
      }
    }
    __syncthreads();
    int lr = lane & 15, kg = lane >> 4;
    bf16x8 af[4], bfr[4];
    #pragma unroll
    for (int f=0; f<4; ++f){
      int ra = wm + f*16 + lr;
      int rb = wn + f*16 + lr;
      af[f]  = *(const bf16x8*)&AsH[ra*32 + (kg ^ ((ra>>1)&3))*8];
      bfr[f] = *(const bf16x8*)&BsH[rb*32 + (kg ^ ((rb>>1)&3))*8];
    }
    if (SPLITA){
      bf16x8 al[4];
      #pragma unroll
      for (int f=0; f<4; ++f){
        int ra = wm + f*16 + lr;
        al[f] = *(const bf16x8*)&AsL[ra*32 + (kg ^ ((ra>>1)&3))*8];
      }
      #pragma unroll
      for (int mf=0; mf<4; ++mf)
        #pragma unroll
        for (int nf=0; nf<4; ++nf){
          acc[mf][nf] = __builtin_amdgcn_mfma_f32_16x16x32_bf16(af[mf], bfr[nf], acc[mf][nf], 0,0,0);
          acc[mf][nf] = __builtin_amdgcn_mfma_f32_16x16x32_bf16(al[mf], bfr[nf], acc[mf][nf], 0,0,0);
        }
    } else {
      #pragma unroll
      for (int mf=0; mf<4; ++mf)
        #pragma unroll
        for (int nf=0; nf<4; ++nf)
          acc[mf][nf] = __builtin_amdgcn_mfma_f32_16x16x32_bf16(af[mf], bfr[nf], acc[mf][nf], 0,0,0);
    }
    __syncthreads();
  }
  int lr = lane & 15, l4 = (lane >> 4)*4;
  if (ssq){
    float s = 0.f;
    #pragma unroll
    for (int mf=0; mf<4; ++mf)
      #pragma unroll
      for (int nf=0; nf<4; ++nf)
        #pragma unroll
        for (int r=0; r<4; ++r){ float v = acc[mf][nf][r]; s += v*v; }
    s = wsum_f(s);
    if (lane == 0) atomicAdd(ssq, s);
    return;
  }
  #pragma unroll
  for (int mf=0; mf<4; ++mf){
    #pragma unroll
    for (int nf=0; nf<4; ++nf){
      int n = n0 + wn + nf*16 + lr;
      float bv = BR ? bias[n] : 0.f;
      #pragma unroll
      for (int r=0; r<4; ++r){
        int m = m0 + wm + mf*16 + l4 + r;
        float v = acc[mf][nf][r];
        if (BR) v = fmaxf(v + bv, 0.f);
        if (C)  C[coff + (long)bz*sC + (long)m*N + n] = v;
        if (Cb) Cb[(long)bz*sC + (long)m*N + n] = bf_rne(v);
      }
    }
  }
}

// sum S split-K partial slabs, square, wave-reduce, atomic accumulate
__global__ __launch_bounds__(256) void redssq_kernel(const float* __restrict__ P,
    long n, int S, long stride, float* __restrict__ tgt)
{
  __shared__ float ps[4];
  long i = (long)blockIdx.x*256 + threadIdx.x;
  float s = 0.f;
  if (i < n){
    float v = 0.f;
    for (int q=0;q<S;++q) v += P[i + (long)q*stride];
    s = v*v;
  }
  s = wsum_f(s);
  int lane = threadIdx.x & 63, wid = threadIdx.x >> 6;
  if (lane == 0) ps[wid] = s;
  __syncthreads();
  if (threadIdx.x == 0) atomicAdd(tgt, ps[0]+ps[1]+ps[2]+ps[3]);
}

// ------------------------- misc kernels -------------------------
__global__ __launch_bounds__(256) void rownorm_kernel(const float* __restrict__ X,
    float* __restrict__ xx)
{
  int lane = threadIdx.x & 63;
  long row = (long)blockIdx.x*4 + (threadIdx.x >> 6);
  const float* p = X + row*128;
  float v0 = p[lane], v1 = p[64+lane];
  float s = wsum_f(v0*v0 + v1*v1);
  if (lane == 0) xx[row] = s;
}

__global__ __launch_bounds__(128) void reeb_pool_kernel(const float* __restrict__ out1,
    const int* __restrict__ sccs, float* __restrict__ VfR,
    ushort* __restrict__ Hh, ushort* __restrict__ Ll)
{
  int q = blockIdx.x;
  int br = ((q & 7) << 7) + (q >> 3);   // XCD swizzle
  int b = br >> 6;
  int f = threadIdx.x;
  const int* sp = sccs + (long)br*NS;
  const float* ob = out1 + ((long)b << 11)*128;
  float m = -1e30f;
  for (int s=0;s<NS;++s){
    int idx = sp[s];
    m = fmaxf(m, ob[(long)idx*128 + f]);
  }
  long oidx = (long)br*128 + f;
  VfR[oidx] = m;
  ushort h, l; bf_hilo(m, h, l);
  Hh[oidx] = h; Ll[oidx] = l;
}

template<int W, bool PACK>
__global__ __launch_bounds__((W>=256)?256:W) void reeb_mm_kernel(const float* __restrict__ Lap,
    const float* __restrict__ X, const float* __restrict__ T0, float* __restrict__ Y,
    ushort* __restrict__ Hh, ushort* __restrict__ Ll,
    float cs, float c2)
{
  constexpr int TPB = (W>=256)?256:W;
  constexpr int E = W/TPB;
  int br = blockIdx.x; int b = br >> 6; int r = br & 63;
  const float* lr = Lap + ((long)b*NR + r)*NR;
  const float* Xb = X + (long)b*NR*W;
  int tid = threadIdx.x;
  float acc[E] = {};
  for (int q=0;q<NR;++q){
    float w = lr[q];
    #pragma unroll
    for (int e=0;e<E;++e) acc[e] += w * Xb[(long)q*W + tid + e*TPB];
  }
  #pragma unroll
  for (int e=0;e<E;++e){
    long idx = (long)br*W + tid + e*TPB;
    float y = cs*acc[e] + c2*T0[idx];
    Y[idx] = y;
    if (PACK){
      ushort h, l; bf_hilo(y, h, l);
      Hh[idx] = h; Ll[idx] = l;
    }
  }
}

__global__ __launch_bounds__(512) void maxpool1_kernel(const float* __restrict__ X,
    float* __restrict__ part)
{
  int b = blockIdx.x, rc = blockIdx.y; int f = threadIdx.x;
  const float* p = X + ((long)b*2048 + (long)rc*256)*512 + f;
  float m = -1e30f;
  #pragma unroll 4
  for (int r=0;r<256;++r) m = fmaxf(m, p[(long)r*512]);
  part[((long)b*8+rc)*512 + f] = m;
}

__global__ __launch_bounds__(512) void maxpool2_kernel(const float* __restrict__ part,
    const float* __restrict__ outR, float* __restrict__ pool)
{
  int b = blockIdx.x; int f = threadIdx.x;
  const float* pp = part + (long)b*8*512 + f;
  float m = -1e30f;
  #pragma unroll
  for (int r=0;r<8;++r) m = fmaxf(m, pp[r*512]);
  pool[(long)b*1024 + 512 + f] = m;
  const float* rp = outR + (long)b*64*512 + f;
  float mr = -1e30f;
  #pragma unroll 4
  for (int r=0;r<64;++r) mr = fmaxf(mr, rp[(long)r*512]);
  pool[(long)b*1024 + f] = mr;
}

template<bool RELU>
__global__ __launch_bounds__(256) void fc_kernel(const float* __restrict__ in,
    const float* __restrict__ W, const float* __restrict__ bias,
    float* __restrict__ out, int IN, int OUT)
{
  __shared__ float red[4][64];
  int b = blockIdx.x, o0 = blockIdx.y*64;
  int tid = threadIdx.x;
  int ol = tid & 63, q = tid >> 6;
  int o = o0 + ol;
  const float* ip = in + (long)b*IN;
  float acc = 0.f;
  if (o < OUT){
    int kb = IN >> 2;
    int ks = q*kb;
    for (int i=0;i<kb;i+=8){
      #pragma unroll
      for (int u=0;u<8;++u){
        int k = ks + i + u;
        acc += ip[k]*W[(long)k*OUT + o];
      }
    }
  }
  red[q][ol] = acc;
  __syncthreads();
  if (tid < 64){
    int oo = o0 + tid;
    if (oo < OUT){
      float s = red[0][tid]+red[1][tid]+red[2][tid]+red[3][tid] + bias[oo];
      out[(long)b*OUT + oo] = RELU ? fmaxf(s, 0.f) : s;
    }
  }
}

__global__ __launch_bounds__(256) void wreg_kernel(const float* __restrict__ w1,
    const float* __restrict__ b1, const float* __restrict__ w2, const float* __restrict__ b2,
    const float* __restrict__ w3, const float* __restrict__ b3, float* __restrict__ out9)
{
  __shared__ float ps[3][4];
  int tid = threadIdx.x, lane = tid & 63, wid = tid >> 6;
  float s1 = 0.f, s2 = 0.f, s3 = 0.f;
  for (int i=tid;i<1024;i+=256){ float v = w1[(long)i*512]; s1 += v*v; }
  for (int i=tid;i<512;i+=256){ float v = w2[(long)i*128]; s2 += v*v; }
  if (tid < 128){ float v = w3[(long)tid*40]; s3 = v*v; }
  s1 = wsum_f(s1); s2 = wsum_f(s2); s3 = wsum_f(s3);
  if (lane == 0){ ps[0][wid]=s1; ps[1][wid]=s2; ps[2][wid]=s3; }
  __syncthreads();
  if (tid == 0){
    out9[3] = ps[0][0]+ps[0][1]+ps[0][2]+ps[0][3];
    out9[4] = b1[0]*b1[0];
    out9[5] = ps[1][0]+ps[1][1]+ps[1][2]+ps[1][3];
    out9[6] = b2[0]*b2[0];
    out9[7] = ps[2][0]+ps[2][1]+ps[2][2]+ps[2][3];
    out9[8] = b3[0]*b3[0];
  }
}

// ------------------------- host orchestration -------------------------
extern "C" void kernel_launch(void* const* d_in, const int* in_sizes, int n_in,
                              void* d_out, int out_size, void* d_ws, size_t ws_size,
                              hipStream_t stream)
{
  (void)in_sizes; (void)n_in; (void)d_ws; (void)ws_size; (void)out_size;
  const float* x    = (const float*)d_in[0];
  const float* lapR = (const float*)d_in[1];
  const int*   sccs = (const int*)d_in[2];
  const float* w1   = (const float*)d_in[9];
  const float* b1   = (const float*)d_in[10];
  const float* w2   = (const float*)d_in[11];
  const float* b2   = (const float*)d_in[12];
  const float* wR   = (const float*)d_in[13];
  const float* bRb  = (const float*)d_in[14];
  const float* fw1  = (const float*)d_in[15];
  const float* fb1  = (const float*)d_in[16];
  const float* fw2  = (const float*)d_in[17];
  const float* fb2  = (const float*)d_in[18];
  const float* fw3  = (const float*)d_in[19];
  const float* fb3  = (const float*)d_in[20];
  float* out = (float*)d_out;

  float* Fb = nullptr; int* Ib = nullptr; ushort* Ub = nullptr;
  hipGetSymbolAddress((void**)&Fb, HIP_SYMBOL(g_farena));
  hipGetSymbolAddress((void**)&Ib, HIP_SYMBOL(g_iarena));
  hipGetSymbolAddress((void**)&Ub, HIP_SYMBOL(g_uarena));

  float* out1 = Fb + aOUT1;  float* t1a = Fb + aT1A;  float* t2a = Fb + aT2A;
  float* Z1   = Fb + aZ1;
  float* vals1= Fb + aVALS1; float* dis1= Fb + aDIS1;
  float* vals2= Fb + aVALS2; float* dis2= Fb + aDIS2;
  float* xx2  = Fb + aXX2;   float* xx1 = Fb + aXX1;
  float* t1b  = Fb + aT1B;   float* t2b = Fb + aT2B;
  float* out2 = Fb + aOUT2;  float* Z2  = Fb + aZ2;
  float* VfR  = Fb + aVFR;   float* t1R = Fb + aT1R;  float* t2R= Fb + aT2R;
  float* outR = Fb + aOUTR;  float* ZR  = Fb + aZR;
  float* pool = Fb + aPOOL;  float* fc1o= Fb + aFC1O; float* fc2o=Fb + aFC2O;
  float* mpp  = Fb + aMPP;   float* M1p = Fb + aM1P;  float* M2p = Fb + aM2P;
  int* cols1 = Ib + iCOLS1; int* cnt1 = Ib + iCNT1;
  int* cols2 = Ib + iCOLS2; int* cnt2 = Ib + iCNT2;
  ushort* out1h = Ub + uOUT1H; ushort* out1l = Ub + uOUT1L;
  ushort* out1r = Ub + uOUT1R;
  ushort* t1bh  = Ub + uT1BH;  ushort* t1bl  = Ub + uT1BL;
  ushort* t2bh  = Ub + uT2BH;  ushort* t2bl  = Ub + uT2BL;
  ushort* w2t   = Ub + uW2T;
  ushort* vfrh  = Ub + uVFRH;  ushort* vfrl  = Ub + uVFRL;
  ushort* t1rh  = Ub + uT1RH;  ushort* t1rl  = Ub + uT1RL;
  ushort* t2rh  = Ub + uT2RH;  ushort* t2rl  = Ub + uT2RL;
  ushort* wrt   = Ub + uWRT;
  ushort* out1t = Ub + uOUT1T; ushort* z1t   = Ub + uZ1T;
  ushort* out2t = Ub + uOUT2T; ushort* z2t   = Ub + uZ2T;
  ushort* outrt = Ub + uOUTRT; ushort* zrt   = Ub + uZRT;
  ushort* out2b = Ub + uOUT2B; ushort* Gb16  = Ub + uG;

  hipMemsetAsync(out + 640, 0, 9*sizeof(float), stream);

  // ---- graph 1 (x, FIN=6) ----
  xx6_kernel<<<dim3(128),dim3(256),0,stream>>>(x, xx1);
  knn1_kernel<<<dim3(8192),dim3(256),0,stream>>>(x, xx1, cols1, vals1, cnt1, dis1);
  spmm6_kernel<<<dim3(128),dim3(256),0,stream>>>(x, x, t1a, cols1, vals1, cnt1, dis1, 1.f, 0.f, 1.f);
  spmm6_kernel<<<dim3(128),dim3(256),0,stream>>>(t1a, x, t2a, cols1, vals1, cnt1, dis1, 2.f, -1.f, 2.f);
  conv1_kernel<<<dim3(32768),dim3(128),0,stream>>>(x, t1a, t2a, w1, b1, out1, out1h, out1l, out1r);

  // reg1 = ||out1^T (L1 out1)||^2 (single-bf16, split-K partials + reduce)
  spmm_kernel<128,false><<<dim3(32768),dim3(128),0,stream>>>(out1, out1, Z1, nullptr, nullptr,
      cols1, vals1, cnt1, dis1, 1.f, 0.f, 1.f);
  tpack_kernel<false><<<dim3(4,64,16),dim3(256),0,stream>>>(out1, out1t, nullptr, 2048,128, 2048L*128, 128L*2048);
  tpack_kernel<false><<<dim3(4,64,16),dim3(256),0,stream>>>(Z1,   z1t,   nullptr, 2048,128, 2048L*128, 128L*2048);
  mgemm_kernel<false,false,false><<<dim3(1,1,128),dim3(256),0,stream>>>(
      out1t,nullptr,nullptr, nullptr,nullptr,nullptr, z1t, nullptr, M1p,
      nullptr, nullptr, 128,128,2048, 128L*2048, 128L*2048, 128L*128, 256, 16L*128*128);
  redssq_kernel<<<dim3(1024),dim3(256),0,stream>>>(M1p, 16L*128*128, 8, 16L*128*128, out+640);
  reeb_pool_kernel<<<dim3(1024),dim3(128),0,stream>>>(out1, sccs, VfR, vfrh, vfrl);

  // ---- graph 2: full dense bf16 Gram (L3-resident) + one knn2 ----
  rownorm_kernel<<<dim3(8192),dim3(256),0,stream>>>(out1, xx2);
  mgemm_kernel<false,false,false><<<dim3(16,16,16),dim3(256),0,stream>>>(
      out1r,nullptr,nullptr, nullptr,nullptr,nullptr, out1r, nullptr, nullptr,
      Gb16, nullptr, 2048,2048,128, (long)NP*128, (long)NP*128, (long)NP*NP, 0, 0);
  knn2_kernel<<<dim3(8192),dim3(256),0,stream>>>(Gb16, xx2, cols2, vals2, cnt2, dis2);

  spmm_kernel<128,true><<<dim3(32768),dim3(128),0,stream>>>(out1, out1, t1b, t1bh, t1bl,
      cols2, vals2, cnt2, dis2, 1.f, 0.f, 1.f);
  spmm_kernel<128,true><<<dim3(32768),dim3(128),0,stream>>>(t1b, out1, t2b, t2bh, t2bl,
      cols2, vals2, cnt2, dis2, 2.f, -1.f, 2.f);
  tpack_kernel<false><<<dim3(16,12,1),dim3(256),0,stream>>>(w2, w2t, nullptr, 384,512, 0,0);
  mgemm_kernel<true,true,true><<<dim3(256,4,1),dim3(256),0,stream>>>(
      out1h,t1bh,t2bh, out1l,t1bl,t2bl, w2t, b2, out2,
      out2b, nullptr, 32768,512,384, 0,0,0, 0, 0);
  // reg2 (split-K x4 partials + reduce)
  spmmb_kernel<<<dim3(8192),dim3(256),0,stream>>>(out2, out2b, Z2, cols2, vals2, cnt2, dis2);
  tpack_kernel<false><<<dim3(16,64,16),dim3(256),0,stream>>>(out2, out2t, nullptr, 2048,512, 2048L*512, 512L*2048);
  tpack_kernel<false><<<dim3(16,64,16),dim3(256),0,stream>>>(Z2,   z2t,   nullptr, 2048,512, 2048L*512, 512L*2048);
  mgemm_kernel<false,false,false><<<dim3(4,4,64),dim3(256),0,stream>>>(
      out2t,nullptr,nullptr, nullptr,nullptr,nullptr, z2t, nullptr, M2p,
      nullptr, nullptr, 512,512,2048, 512L*2048, 512L*2048, 512L*512, 512, 16L*512*512);
  redssq_kernel<<<dim3(16384),dim3(256),0,stream>>>(M2p, 16L*512*512, 4, 16L*512*512, out+641);

  // ---- Reeb branch ----
  reeb_mm_kernel<128,true><<<dim3(1024),dim3(128),0,stream>>>(lapR, VfR, VfR, t1R, t1rh, t1rl, 1.f, 0.f);
  reeb_mm_kernel<128,true><<<dim3(1024),dim3(128),0,stream>>>(lapR, t1R, VfR, t2R, t2rh, t2rl, 2.f, -1.f);
  tpack_kernel<false><<<dim3(16,12,1),dim3(256),0,stream>>>(wR, wrt, nullptr, 384,512, 0,0);
  mgemm_kernel<true,true,true><<<dim3(8,4,1),dim3(256),0,stream>>>(
      vfrh,t1rh,t2rh, vfrl,t1rl,t2rl, wrt, bRb, outR,
      nullptr, nullptr, 1024,512,384, 0,0,0, 0, 0);
  reeb_mm_kernel<512,false><<<dim3(1024),dim3(256),0,stream>>>(lapR, outR, outR, ZR, nullptr, nullptr, 1.f, 0.f);
  tpack_kernel<false><<<dim3(16,2,16),dim3(256),0,stream>>>(outR, outrt, nullptr, 64,512, 64L*512, 512L*64);
  tpack_kernel<false><<<dim3(16,2,16),dim3(256),0,stream>>>(ZR,   zrt,   nullptr, 64,512, 64L*512, 512L*64);
  mgemm_kernel<false,false,false><<<dim3(4,4,16),dim3(256),0,stream>>>(
      outrt,nullptr,nullptr, nullptr,nullptr,nullptr, zrt, nullptr, nullptr,
      nullptr, out+642, 512,512,64, 512L*64, 512L*64, 0, 0, 0);

  // ---- head ----
  maxpool1_kernel<<<dim3(16,8),dim3(512),0,stream>>>(out2, mpp);
  maxpool2_kernel<<<dim3(16),dim3(512),0,stream>>>(mpp, outR, pool);
  fc_kernel<true ><<<dim3(16,8),dim3(256),0,stream>>>(pool, fw1, fb1, fc1o, 1024, 512);
  fc_kernel<true ><<<dim3(16,2),dim3(256),0,stream>>>(fc1o, fw2, fb2, fc2o, 512, 128);
  fc_kernel<false><<<dim3(16,1),dim3(256),0,stream>>>(fc2o, fw3, fb3, out, 128, 40);
  wreg_kernel<<<dim3(1),dim3(256),0,stream>>>(fw1, fb1, fw2, fb2, fw3, fb3, out+640);
}

// Round 11
// 1057.574 us; speedup vs baseline: 1.1781x; 1.1781x over previous
//
#include <hip/hip_runtime.h>

#define NB 16
#define NP 2048
#define NR 64
#define NS 64
#define KSEL 40

typedef __attribute__((ext_vector_type(8))) short bf16x8;
typedef __attribute__((ext_vector_type(4))) float f32x4;

// ------------------------- static scratch arenas -------------------------
constexpr long aOUT1 = 0;
constexpr long aT1A  = aOUT1 + 16L*2048*128;
constexpr long aT2A  = aT1A  + 16L*2048*6;
constexpr long aZ1   = aT2A  + 16L*2048*6;
constexpr long aVALS1= aZ1   + 16L*2048*128;
constexpr long aDIS1 = aVALS1+ 16L*2048*64;
constexpr long aVALS2= aDIS1 + 16L*2048;
constexpr long aDIS2 = aVALS2+ 16L*2048*64;
constexpr long aXX2  = aDIS2 + 16L*2048;
constexpr long aXX1  = aXX2  + 16L*2048;
constexpr long aT1B  = aXX1  + 16L*2048;
constexpr long aT2B  = aT1B  + 16L*2048*128;
constexpr long aOUT2 = aT2B  + 16L*2048*128;
constexpr long aZ2   = aOUT2 + 16L*2048*512;
constexpr long aVFR  = aZ2   + 16L*2048*512;
constexpr long aT1R  = aVFR  + 16L*64*128;
constexpr long aT2R  = aT1R  + 16L*64*128;
constexpr long aOUTR = aT2R  + 16L*64*128;
constexpr long aZR   = aOUTR + 16L*64*512;
constexpr long aPOOL = aZR   + 16L*64*512;
constexpr long aFC1O = aPOOL + 16L*1024;
constexpr long aFC2O = aFC1O + 16L*512;
constexpr long aMPP  = aFC2O + 16L*128;
constexpr long aM1P  = aMPP  + 16L*8*512;
constexpr long aM2P  = aM1P  + 8L*16*128*128;
constexpr long FTOT  = aM2P  + 4L*16*512*512;

constexpr long iCOLS1 = 0;
constexpr long iCNT1  = iCOLS1 + 16L*2048*64;
constexpr long iCOLS2 = iCNT1  + 16L*2048;
constexpr long iCNT2  = iCOLS2 + 16L*2048*64;
constexpr long ITOT   = iCNT2  + 16L*2048;

// bf16 (ushort) arena
constexpr long uOUT1H = 0;
constexpr long uOUT1L = uOUT1H + 16L*2048*128;
constexpr long uOUT1R = uOUT1L + 16L*2048*128;
constexpr long uT1BH  = uOUT1R + 16L*2048*128;
constexpr long uT1BL  = uT1BH  + 16L*2048*128;
constexpr long uT2BH  = uT1BL  + 16L*2048*128;
constexpr long uT2BL  = uT2BH  + 16L*2048*128;
constexpr long uW2T   = uT2BL  + 16L*2048*128;
constexpr long uVFRH  = uW2T   + 512L*384;
constexpr long uVFRL  = uVFRH  + 16L*64*128;
constexpr long uT1RH  = uVFRL  + 16L*64*128;
constexpr long uT1RL  = uT1RH  + 16L*64*128;
constexpr long uT2RH  = uT1RL  + 16L*64*128;
constexpr long uT2RL  = uT2RH  + 16L*64*128;
constexpr long uWRT   = uT2RL  + 16L*64*128;
constexpr long uOUT1T = uWRT   + 512L*384;
constexpr long uZ1T   = uOUT1T + 16L*128*2048;
constexpr long uOUT2T = uZ1T   + 16L*128*2048;
constexpr long uZ2T   = uOUT2T + 16L*512*2048;
constexpr long uOUTRT = uZ2T   + 16L*512*2048;
constexpr long uZRT   = uOUTRT + 16L*512*64;
constexpr long uOUT2B = uZRT   + 16L*512*64;
constexpr long uG     = uOUT2B + 16L*2048*512;
constexpr long UTOT   = uG     + 16L*2048*2048;

__device__ __align__(256) float  g_farena[FTOT];
__device__ __align__(256) int    g_iarena[ITOT];
__device__ __align__(256) ushort g_uarena[UTOT];

// ------------------------- helpers -------------------------
__device__ __forceinline__ float wsum_f(float v){
  #pragma unroll
  for (int s=32;s>0;s>>=1) v += __shfl_xor(v, s, 64);
  return v;
}
__device__ __forceinline__ int wsum_i(int v){
  #pragma unroll
  for (int s=32;s>0;s>>=1) v += __shfl_xor(v, s, 64);
  return v;
}

__device__ __forceinline__ void gl2lds16(const void* g, void* l){
  __builtin_amdgcn_global_load_lds(
      (const __attribute__((address_space(1))) void*)g,
      (__attribute__((address_space(3))) void*)l, 16, 0, 0);
}

__device__ __forceinline__ ushort bf_rne(float x){
  unsigned u = __float_as_uint(x);
  u += 0x7fffu + ((u >> 16) & 1u);
  return (ushort)(u >> 16);
}
__device__ __forceinline__ void bf_hilo(float x, ushort& h, ushort& l){
  unsigned u = __float_as_uint(x);
  h = (ushort)(u >> 16);
  float hf = __uint_as_float(u & 0xffff0000u);
  l = (ushort)(__float_as_uint(x - hf) >> 16);
}
__device__ __forceinline__ float bf2f(ushort u){
  return __uint_as_float(((unsigned)u) << 16);
}

// ------------------------- top-k machinery -------------------------
// KSEL-smallest selection over 2048 POSITIVE dist floats (32/lane).
__device__ __forceinline__ void topk_store(float (&dk)[32], int lane, long row,
    int* __restrict__ cols, float* __restrict__ vals,
    int* __restrict__ cnt, float* __restrict__ dis)
{
  float dmin = dk[0], dmax = dk[0];
  #pragma unroll
  for (int q=1;q<32;++q){ dmin = fminf(dmin, dk[q]); dmax = fmaxf(dmax, dk[q]); }
  #pragma unroll
  for (int s=32;s>0;s>>=1){
    dmin = fminf(dmin, __shfl_xor(dmin, s, 64));
    dmax = fmaxf(dmax, __shfl_xor(dmax, s, 64));
  }
  int c0 = 0;
  #pragma unroll
  for (int q=0;q<32;++q) c0 += (int)__popcll(__ballot(dk[q] <= dmin));
  float kth;
  if (c0 >= KSEL){
    kth = dmin;
  } else {
    float lo = dmin, hi = dmax;
    int cLo = c0, cHi = 2048, it = 0;
    while (cHi != KSEL && __float_as_uint(hi) - __float_as_uint(lo) > 1u){
      float t;
      if (it & 1){
        t = __uint_as_float((__float_as_uint(lo) + __float_as_uint(hi)) >> 1);
      } else {
        t = lo + (hi - lo) * ((float)(KSEL - cLo) / (float)(cHi - cLo));
        unsigned tb = __float_as_uint(t);
        unsigned lb = __float_as_uint(lo), hb = __float_as_uint(hi);
        if (tb <= lb) tb = lb + 1u;
        else if (tb >= hb) tb = hb - 1u;
        t = __uint_as_float(tb);
      }
      ++it;
      int c = 0;
      #pragma unroll
      for (int q=0;q<32;++q) c += (int)__popcll(__ballot(dk[q] <= t));
      if (c >= KSEL){ hi = t; cHi = c; } else { lo = t; cLo = c; }
    }
    kth = hi;
  }
  int kc = 0;
  #pragma unroll
  for (int q=0;q<32;++q) kc += (dk[q] <= kth) ? 1 : 0;
  int tot = wsum_i(kc);
  int incl = kc;
  #pragma unroll
  for (int s=1;s<64;s<<=1){ int u = __shfl_up(incl, s, 64); if (lane >= s) incl += u; }
  int pos = incl - kc;
  int* cp = cols + row*64; float* vp = vals + row*64;
  float d = 0.f;
  #pragma unroll
  for (int q=0;q<32;++q){
    if (dk[q] <= kth){
      float v = __expf(-dk[q]);
      d += v;
      if (pos < 64){ cp[pos] = q*64 + lane; vp[pos] = v; }
      pos++;
    }
  }
  d = wsum_f(d);
  if (lane == 0){
    cnt[row] = tot <= 64 ? tot : 64;
    dis[row] = d > 0.f ? (1.0f / sqrtf(fmaxf(d, 1e-12f))) : 0.f;
  }
}

__global__ __launch_bounds__(256) void xx6_kernel(const float* __restrict__ x,
    float* __restrict__ xx1)
{
  long i = (long)blockIdx.x*256 + threadIdx.x;
  const float* p = x + i*6;
  float2 v0 = *(const float2*)(p);
  float2 v1 = *(const float2*)(p+2);
  float2 v2 = *(const float2*)(p+4);
  xx1[i] = v0.x*v0.x + v0.y*v0.y + v1.x*v1.x + v1.y*v1.y + v2.x*v2.x + v2.y*v2.y;
}

__global__ __launch_bounds__(256) void knn1_kernel(const float* __restrict__ x,
    const float* __restrict__ xx1,
    int* __restrict__ cols, float* __restrict__ vals, int* __restrict__ cnt,
    float* __restrict__ dis)
{
  int lane = threadIdx.x & 63;
  long row = (long)blockIdx.x*4 + (threadIdx.x >> 6);
  int b = (int)(row >> 11); int i = (int)(row & (NP-1));
  const float* xb = x + (long)b*NP*6;
  const float* xxb = xx1 + ((long)b << 11);
  float xi[6];
  #pragma unroll
  for (int d2=0; d2<6; ++d2) xi[d2] = xb[(long)i*6 + d2];
  float xxi = xxb[i];
  float dk[32];
  #pragma unroll 4
  for (int c=0;c<32;++c){
    int j = c*64 + lane;
    const float* xj = xb + (long)j*6;
    float2 v0 = *(const float2*)(xj);
    float2 v1 = *(const float2*)(xj+2);
    float2 v2 = *(const float2*)(xj+4);
    float inr = xi[0]*v0.x + xi[1]*v0.y + xi[2]*v1.x + xi[3]*v1.y + xi[4]*v2.x + xi[5]*v2.y;
    dk[c] = fmaxf(xxi + xxb[j] - 2.f*inr, 0.f);
  }
  topk_store(dk, lane, row, cols, vals, cnt, dis);
}

// one launch over all 32768 rows; G is bf16 [16][2048][2048] (L3-resident)
__global__ __launch_bounds__(256) void knn2_kernel(const ushort* __restrict__ G,
    const float* __restrict__ xx,
    int* __restrict__ cols, float* __restrict__ vals, int* __restrict__ cnt,
    float* __restrict__ dis)
{
  int lane = threadIdx.x & 63;
  long row = (long)blockIdx.x*4 + (threadIdx.x >> 6);
  const ushort* Gr = G + row*NP;
  const float* xxb = xx + ((row >> 11) << 11);
  int i = (int)(row & (NP-1));
  float xxi = xxb[i];
  float dk[32];
  #pragma unroll 4
  for (int c=0;c<32;++c){
    int j = c*64 + lane;
    dk[c] = fmaxf(xxi + xxb[j] - 2.f*bf2f(Gr[j]), 0.f);
  }
  topk_store(dk, lane, row, cols, vals, cnt, dis);
}

// ------------------------- sparse L application -------------------------
__global__ __launch_bounds__(256) void spmm6_kernel(const float* __restrict__ X,
    const float* __restrict__ T0, float* __restrict__ Y,
    const int* __restrict__ cols, const float* __restrict__ vals,
    const int* __restrict__ cnt, const float* __restrict__ dis,
    float c1, float c2, float cs)
{
  long row = (long)blockIdx.x*256 + threadIdx.x;
  int b = (int)(row >> 11);
  const float* Xb = X + ((long)b << 11)*6;
  const float* db = dis + ((long)b << 11);
  float acc[6] = {0,0,0,0,0,0};
  int c = cnt[row];
  const int* cp = cols + row*64; const float* vp = vals + row*64;
  for (int t=0;t<c;++t){
    int j = cp[t];
    float w = vp[t] * db[j];
    const float* xr = Xb + (long)j*6;
    #pragma unroll
    for (int d2=0; d2<6; ++d2) acc[d2] += w * xr[d2];
  }
  float di = dis[row];
  #pragma unroll
  for (int d2=0; d2<6; ++d2)
    Y[row*6+d2] = c1*X[row*6+d2] + c2*T0[row*6+d2] - cs*di*acc[d2];
}

// XCD-swizzled; optionally emits trunc hi/lo bf16 pair of the result.
template<int W, bool PACK>
__global__ __launch_bounds__((W >= 256) ? 256 : W) void spmm_kernel(
    const float* __restrict__ X, const float* __restrict__ T0, float* __restrict__ Y,
    ushort* __restrict__ Hh, ushort* __restrict__ Ll,
    const int* __restrict__ cols, const float* __restrict__ vals,
    const int* __restrict__ cnt, const float* __restrict__ dis,
    float c1, float c2, float cs)
{
  constexpr int TPB = (W >= 256) ? 256 : W;
  constexpr int E = W / TPB;
  __shared__ int scol[64];
  __shared__ float sval[64];
  int q = blockIdx.x;
  long row = ((long)(q & 7) << 12) + (q >> 3);
  int b = (int)(row >> 11);
  int tid = threadIdx.x;
  int c = cnt[row];
  if (tid < 64){ scol[tid] = cols[row*64+tid]; sval[tid] = vals[row*64+tid]; }
  __syncthreads();
  const float* Xb = X + ((long)b << 11)*W;
  const float* db = dis + ((long)b << 11);
  float acc[E] = {};
  for (int t=0;t<c;++t){
    int j = scol[t];
    float w = sval[t] * db[j];
    const float* xr = Xb + (long)j*W;
    #pragma unroll
    for (int e=0;e<E;++e) acc[e] += w * xr[tid + e*TPB];
  }
  float di = dis[row];
  #pragma unroll
  for (int e=0;e<E;++e){
    long idx = row*W + tid + e*TPB;
    float y = c1*X[idx] + c2*T0[idx] - cs*di*acc[e];
    Y[idx] = y;
    if (PACK){
      ushort h, l; bf_hilo(y, h, l);
      Hh[idx] = h; Ll[idx] = l;
    }
  }
}

// Z = X - diag(dis) S X with bf16 gather source (reg-norm path only).
__global__ __launch_bounds__(256) void spmmb_kernel(
    const float* __restrict__ X, const ushort* __restrict__ Xb,
    float* __restrict__ Y,
    const int* __restrict__ cols, const float* __restrict__ vals,
    const int* __restrict__ cnt, const float* __restrict__ dis)
{
  __shared__ int scol[4][64];
  __shared__ float sval[4][64];
  int q = blockIdx.x;
  int wid = threadIdx.x >> 6, lane = threadIdx.x & 63;
  long row = ((long)(q & 7) << 12) + ((long)(q >> 3) << 2) + wid;
  int b = (int)(row >> 11);
  scol[wid][lane] = cols[row*64 + lane];
  sval[wid][lane] = vals[row*64 + lane];
  const ushort* Xbb = Xb + ((long)b << 11)*512;
  const float* db = dis + ((long)b << 11);
  int c = cnt[row];
  float acc[8] = {};
  for (int t=0;t<c;++t){
    int j = scol[wid][t];
    float w = sval[wid][t] * db[j];
    bf16x8 v = *(const bf16x8*)(Xbb + (long)j*512 + lane*8);
    #pragma unroll
    for (int e=0;e<8;++e)
      acc[e] += w * bf2f((ushort)v[e]);
  }
  float di = dis[row];
  long base = row*512 + lane*8;
  float4 x0 = *(const float4*)(X + base);
  float4 x1 = *(const float4*)(X + base + 4);
  float4 o0, o1;
  o0.x = x0.x - di*acc[0]; o0.y = x0.y - di*acc[1];
  o0.z = x0.z - di*acc[2]; o0.w = x0.w - di*acc[3];
  o1.x = x1.x - di*acc[4]; o1.y = x1.y - di*acc[5];
  o1.z = x1.z - di*acc[6]; o1.w = x1.w - di*acc[7];
  *(float4*)(Y + base) = o0;
  *(float4*)(Y + base + 4) = o1;
}

// ------------------------- conv1 (K=18, direct; fused bf16 packs) --------
__global__ __launch_bounds__(128) void conv1_kernel(const float* __restrict__ x,
    const float* __restrict__ t1, const float* __restrict__ t2,
    const float* __restrict__ w, const float* __restrict__ bias,
    float* __restrict__ out, ushort* __restrict__ oh, ushort* __restrict__ ol,
    ushort* __restrict__ orr)
{
  long row = blockIdx.x; int o = threadIdx.x;
  float acc = bias[o];
  const float* xr = x + row*6; const float* a1 = t1 + row*6; const float* a2 = t2 + row*6;
  #pragma unroll
  for (int d2=0; d2<6; ++d2){
    acc += xr[d2]*w[d2*128 + o];
    acc += a1[d2]*w[(6+d2)*128 + o];
    acc += a2[d2]*w[(12+d2)*128 + o];
  }
  acc = fmaxf(acc, 0.f);
  long idx = row*128 + o;
  out[idx] = acc;
  ushort h, l; bf_hilo(acc, h, l);
  oh[idx] = h; ol[idx] = l;
  orr[idx] = bf_rne(acc);
}

// transpose fp32 [R][C] -> bf16 [C][R]; HILO: trunc hi/lo pair, else RNE
template<bool HILO>
__global__ __launch_bounds__(256) void tpack_kernel(const float* __restrict__ X,
    ushort* __restrict__ H, ushort* __restrict__ L,
    int R, int C, long sIn, long sOut)
{
  __shared__ float tile[32][33];
  int c0 = blockIdx.x*32, r0 = blockIdx.y*32, b = blockIdx.z;
  const float* Xb = X + (long)b*sIn;
  int tx = threadIdx.x & 31, ty = threadIdx.x >> 5;
  #pragma unroll
  for (int rr=ty; rr<32; rr+=8)
    tile[rr][tx] = Xb[(long)(r0+rr)*C + c0+tx];
  __syncthreads();
  #pragma unroll
  for (int cc=ty; cc<32; cc+=8){
    float xv = tile[tx][cc];
    long oidx = (long)b*sOut + (long)(c0+cc)*R + r0 + tx;
    if (HILO){
      ushort h, l; bf_hilo(xv, h, l);
      H[oidx] = h; L[oidx] = l;
    } else {
      H[oidx] = bf_rne(xv);
    }
  }
}

// ------------------------- bf16 MFMA GEMM (global_load_lds + swizzle) ----
// C[m][n] = sum_k A[m][k]*B[n][k]. SPLITA: A=Ah+Al (2 MFMA, B single).
// C (fp32) and Cb (bf16) stores both optional. ssq: atomicAdd ||C||^2 only.
// kchunk>0: split-K — blockIdx.z = split*16 + batch, K range [split*kchunk,+kchunk),
// C partial slab at C + split*sSplit.
template<bool SPLITA, bool CHEB, bool BR>
__global__ __launch_bounds__(256) void mgemm_kernel(
    const ushort* __restrict__ Ah0, const ushort* __restrict__ Ah1, const ushort* __restrict__ Ah2,
    const ushort* __restrict__ Al0, const ushort* __restrict__ Al1, const ushort* __restrict__ Al2,
    const ushort* __restrict__ Bh,
    const float* __restrict__ bias, float* __restrict__ C,
    ushort* __restrict__ Cb, float* __restrict__ ssq,
    int M, int N, int K, long sA, long sB, long sC,
    int kchunk, long sSplit)
{
  __shared__ ushort AsH[128*32];
  __shared__ ushort BsH[128*32];
  __shared__ ushort AsL[SPLITA ? 128*32 : 8];
  int bz = blockIdx.z;
  int kb = 0, ke = K;
  long coff = 0;
  if (kchunk > 0){
    int split = bz >> 4; bz &= 15;
    kb = split * kchunk;
    ke = kb + kchunk; if (ke > K) ke = K;
    coff = (long)split * sSplit;
  }
  int m0 = blockIdx.x*128, n0 = blockIdx.y*128;
  int tid = threadIdx.x, lane = tid & 63, wid = tid >> 6;
  int wm = (wid & 1)*64, wn = (wid >> 1)*64;
  f32x4 acc[4][4] = {};
  const ushort* Bb = Bh + (long)bz*sB;
  const ushort* Ab = CHEB ? Ah0 : (Ah0 + (long)bz*sA);
  const ushort* Alb = (SPLITA && !CHEB) ? (Al0 + (long)bz*sA) : Al0;

  for (int k0 = kb; k0 < ke; k0 += 32){
    #pragma unroll
    for (int cc2=0; cc2<2; ++cc2){
      int chunk = wid*2 + cc2;
      int e = chunk*512 + lane*8;
      int row = e >> 5;
      int slot = (e >> 3) & 3;
      int scol = (slot ^ ((row >> 1) & 3)) * 8;
      const ushort* asrc;
      if (CHEB){
        int kg2 = k0 + scol;
        const ushort* base = (kg2 < 128) ? Ah0 : ((kg2 < 256) ? Ah1 : Ah2);
        asrc = base + (long)(m0+row)*128 + (kg2 & 127);
      } else {
        asrc = Ab + (long)(m0+row)*K + k0 + scol;
      }
      gl2lds16(asrc, &AsH[chunk*512]);
      gl2lds16(Bb + (long)(n0+row)*K + k0 + scol, &BsH[chunk*512]);
      if (SPLITA){
        const ushort* alsrc;
        if (CHEB){
          int kg2 = k0 + scol;
          const ushort* base = (kg2 < 128) ? Al0 : ((kg2 < 256) ? Al1 : Al2);
          alsrc = base + (long)(m0+row)*128 + (kg2 & 127);
        } else {
          alsrc = Alb + (long)(m0+row)*K + k0 + scol;
        }
        gl2lds16(alsrc, &AsL[chunk*512]);
      }
    }
    __syncthreads();
    int lr = lane & 15, kg = lane >> 4;
    bf16x8 af[4], bfr[4];
    #pragma unroll
    for (int f=0; f<4; ++f){
      int ra = wm + f*16 + lr;
      int rb = wn + f*16 + lr;
      af[f]  = *(const bf16x8*)&AsH[ra*32 + (kg ^ ((ra>>1)&3))*8];
      bfr[f] = *(const bf16x8*)&BsH[rb*32 + (kg ^ ((rb>>1)&3))*8];
    }
    if (SPLITA){
      bf16x8 al[4];
      #pragma unroll
      for (int f=0; f<4; ++f){
        int ra = wm + f*16 + lr;
        al[f] = *(const bf16x8*)&AsL[ra*32 + (kg ^ ((ra>>1)&3))*8];
      }
      #pragma unroll
      for (int mf=0; mf<4; ++mf)
        #pragma unroll
        for (int nf=0; nf<4; ++nf){
          acc[mf][nf] = __builtin_amdgcn_mfma_f32_16x16x32_bf16(af[mf], bfr[nf], acc[mf][nf], 0,0,0);
          acc[mf][nf] = __builtin_amdgcn_mfma_f32_16x16x32_bf16(al[mf], bfr[nf], acc[mf][nf], 0,0,0);
        }
    } else {
      #pragma unroll
      for (int mf=0; mf<4; ++mf)
        #pragma unroll
        for (int nf=0; nf<4; ++nf)
          acc[mf][nf] = __builtin_amdgcn_mfma_f32_16x16x32_bf16(af[mf], bfr[nf], acc[mf][nf], 0,0,0);
    }
    __syncthreads();
  }
  int lr = lane & 15, l4 = (lane >> 4)*4;
  if (ssq){
    float s = 0.f;
    #pragma unroll
    for (int mf=0; mf<4; ++mf)
      #pragma unroll
      for (int nf=0; nf<4; ++nf)
        #pragma unroll
        for (int r=0; r<4; ++r){ float v = acc[mf][nf][r]; s += v*v; }
    s = wsum_f(s);
    if (lane == 0) atomicAdd(ssq, s);
    return;
  }
  #pragma unroll
  for (int mf=0; mf<4; ++mf){
    #pragma unroll
    for (int nf=0; nf<4; ++nf){
      int n = n0 + wn + nf*16 + lr;
      float bv = BR ? bias[n] : 0.f;
      #pragma unroll
      for (int r=0; r<4; ++r){
        int m = m0 + wm + mf*16 + l4 + r;
        float v = acc[mf][nf][r];
        if (BR) v = fmaxf(v + bv, 0.f);
        if (C)  C[coff + (long)bz*sC + (long)m*N + n] = v;
        if (Cb) Cb[(long)bz*sC + (long)m*N + n] = bf_rne(v);
      }
    }
  }
}

// sum S split-K partial slabs, square, reduce. Grid-stride with BOUNDED
// block count (512) -> 512 same-address atomics total (atomic serialization
// at 16K blocks was 212us; 512 is ~7us).
__global__ __launch_bounds__(256) void redssq_kernel(const float* __restrict__ P,
    long n, int S, long stride, float* __restrict__ tgt)
{
  __shared__ float ps[4];
  float s = 0.f;
  for (long i = (long)blockIdx.x*256 + threadIdx.x; i < n; i += (long)gridDim.x*256){
    float v = 0.f;
    for (int q=0;q<S;++q) v += P[i + (long)q*stride];
    s += v*v;
  }
  s = wsum_f(s);
  int lane = threadIdx.x & 63, wid = threadIdx.x >> 6;
  if (lane == 0) ps[wid] = s;
  __syncthreads();
  if (threadIdx.x == 0) atomicAdd(tgt, ps[0]+ps[1]+ps[2]+ps[3]);
}

// ------------------------- misc kernels -------------------------
__global__ __launch_bounds__(256) void rownorm_kernel(const float* __restrict__ X,
    float* __restrict__ xx)
{
  int lane = threadIdx.x & 63;
  long row = (long)blockIdx.x*4 + (threadIdx.x >> 6);
  const float* p = X + row*128;
  float v0 = p[lane], v1 = p[64+lane];
  float s = wsum_f(v0*v0 + v1*v1);
  if (lane == 0) xx[row] = s;
}

__global__ __launch_bounds__(128) void reeb_pool_kernel(const float* __restrict__ out1,
    const int* __restrict__ sccs, float* __restrict__ VfR,
    ushort* __restrict__ Hh, ushort* __restrict__ Ll)
{
  int q = blockIdx.x;
  int br = ((q & 7) << 7) + (q >> 3);   // XCD swizzle
  int b = br >> 6;
  int f = threadIdx.x;
  const int* sp = sccs + (long)br*NS;
  const float* ob = out1 + ((long)b << 11)*128;
  float m = -1e30f;
  for (int s=0;s<NS;++s){
    int idx = sp[s];
    m = fmaxf(m, ob[(long)idx*128 + f]);
  }
  long oidx = (long)br*128 + f;
  VfR[oidx] = m;
  ushort h, l; bf_hilo(m, h, l);
  Hh[oidx] = h; Ll[oidx] = l;
}

template<int W, bool PACK>
__global__ __launch_bounds__((W>=256)?256:W) void reeb_mm_kernel(const float* __restrict__ Lap,
    const float* __restrict__ X, const float* __restrict__ T0, float* __restrict__ Y,
    ushort* __restrict__ Hh, ushort* __restrict__ Ll,
    float cs, float c2)
{
  constexpr int TPB = (W>=256)?256:W;
  constexpr int E = W/TPB;
  int br = blockIdx.x; int b = br >> 6; int r = br & 63;
  const float* lr = Lap + ((long)b*NR + r)*NR;
  const float* Xb = X + (long)b*NR*W;
  int tid = threadIdx.x;
  float acc[E] = {};
  for (int q=0;q<NR;++q){
    float w = lr[q];
    #pragma unroll
    for (int e=0;e<E;++e) acc[e] += w * Xb[(long)q*W + tid + e*TPB];
  }
  #pragma unroll
  for (int e=0;e<E;++e){
    long idx = (long)br*W + tid + e*TPB;
    float y = cs*acc[e] + c2*T0[idx];
    Y[idx] = y;
    if (PACK){
      ushort h, l; bf_hilo(y, h, l);
      Hh[idx] = h; Ll[idx] = l;
    }
  }
}

__global__ __launch_bounds__(512) void maxpool1_kernel(const float* __restrict__ X,
    float* __restrict__ part)
{
  int b = blockIdx.x, rc = blockIdx.y; int f = threadIdx.x;
  const float* p = X + ((long)b*2048 + (long)rc*256)*512 + f;
  float m = -1e30f;
  #pragma unroll 4
  for (int r=0;r<256;++r) m = fmaxf(m, p[(long)r*512]);
  part[((long)b*8+rc)*512 + f] = m;
}

__global__ __launch_bounds__(512) void maxpool2_kernel(const float* __restrict__ part,
    const float* __restrict__ outR, float* __restrict__ pool)
{
  int b = blockIdx.x; int f = threadIdx.x;
  const float* pp = part + (long)b*8*512 + f;
  float m = -1e30f;
  #pragma unroll
  for (int r=0;r<8;++r) m = fmaxf(m, pp[r*512]);
  pool[(long)b*1024 + 512 + f] = m;
  const float* rp = outR + (long)b*64*512 + f;
  float mr = -1e30f;
  #pragma unroll 4
  for (int r=0;r<64;++r) mr = fmaxf(mr, rp[(long)r*512]);
  pool[(long)b*1024 + f] = mr;
}

template<bool RELU>
__global__ __launch_bounds__(256) void fc_kernel(const float* __restrict__ in,
    const float* __restrict__ W, const float* __restrict__ bias,
    float* __restrict__ out, int IN, int OUT)
{
  __shared__ float red[4][64];
  int b = blockIdx.x, o0 = blockIdx.y*64;
  int tid = threadIdx.x;
  int ol = tid & 63, q = tid >> 6;
  int o = o0 + ol;
  const float* ip = in + (long)b*IN;
  float acc = 0.f;
  if (o < OUT){
    int kb = IN >> 2;
    int ks = q*kb;
    for (int i=0;i<kb;i+=8){
      #pragma unroll
      for (int u=0;u<8;++u){
        int k = ks + i + u;
        acc += ip[k]*W[(long)k*OUT + o];
      }
    }
  }
  red[q][ol] = acc;
  __syncthreads();
  if (tid < 64){
    int oo = o0 + tid;
    if (oo < OUT){
      float s = red[0][tid]+red[1][tid]+red[2][tid]+red[3][tid] + bias[oo];
      out[(long)b*OUT + oo] = RELU ? fmaxf(s, 0.f) : s;
    }
  }
}

__global__ __launch_bounds__(256) void wreg_kernel(const float* __restrict__ w1,
    const float* __restrict__ b1, const float* __restrict__ w2, const float* __restrict__ b2,
    const float* __restrict__ w3, const float* __restrict__ b3, float* __restrict__ out9)
{
  __shared__ float ps[3][4];
  int tid = threadIdx.x, lane = tid & 63, wid = tid >> 6;
  float s1 = 0.f, s2 = 0.f, s3 = 0.f;
  for (int i=tid;i<1024;i+=256){ float v = w1[(long)i*512]; s1 += v*v; }
  for (int i=tid;i<512;i+=256){ float v = w2[(long)i*128]; s2 += v*v; }
  if (tid < 128){ float v = w3[(long)tid*40]; s3 = v*v; }
  s1 = wsum_f(s1); s2 = wsum_f(s2); s3 = wsum_f(s3);
  if (lane == 0){ ps[0][wid]=s1; ps[1][wid]=s2; ps[2][wid]=s3; }
  __syncthreads();
  if (tid == 0){
    out9[3] = ps[0][0]+ps[0][1]+ps[0][2]+ps[0][3];
    out9[4] = b1[0]*b1[0];
    out9[5] = ps[1][0]+ps[1][1]+ps[1][2]+ps[1][3];
    out9[6] = b2[0]*b2[0];
    out9[7] = ps[2][0]+ps[2][1]+ps[2][2]+ps[2][3];
    out9[8] = b3[0]*b3[0];
  }
}

// ------------------------- host orchestration -------------------------
extern "C" void kernel_launch(void* const* d_in, const int* in_sizes, int n_in,
                              void* d_out, int out_size, void* d_ws, size_t ws_size,
                              hipStream_t stream)
{
  (void)in_sizes; (void)n_in; (void)d_ws; (void)ws_size; (void)out_size;
  const float* x    = (const float*)d_in[0];
  const float* lapR = (const float*)d_in[1];
  const int*   sccs = (const int*)d_in[2];
  const float* w1   = (const float*)d_in[9];
  const float* b1   = (const float*)d_in[10];
  const float* w2   = (const float*)d_in[11];
  const float* b2   = (const float*)d_in[12];
  const float* wR   = (const float*)d_in[13];
  const float* bRb  = (const float*)d_in[14];
  const float* fw1  = (const float*)d_in[15];
  const float* fb1  = (const float*)d_in[16];
  const float* fw2  = (const float*)d_in[17];
  const float* fb2  = (const float*)d_in[18];
  const float* fw3  = (const float*)d_in[19];
  const float* fb3  = (const float*)d_in[20];
  float* out = (float*)d_out;

  float* Fb = nullptr; int* Ib = nullptr; ushort* Ub = nullptr;
  hipGetSymbolAddress((void**)&Fb, HIP_SYMBOL(g_farena));
  hipGetSymbolAddress((void**)&Ib, HIP_SYMBOL(g_iarena));
  hipGetSymbolAddress((void**)&Ub, HIP_SYMBOL(g_uarena));

  float* out1 = Fb + aOUT1;  float* t1a = Fb + aT1A;  float* t2a = Fb + aT2A;
  float* Z1   = Fb + aZ1;
  float* vals1= Fb + aVALS1; float* dis1= Fb + aDIS1;
  float* vals2= Fb + aVALS2; float* dis2= Fb + aDIS2;
  float* xx2  = Fb + aXX2;   float* xx1 = Fb + aXX1;
  float* t1b  = Fb + aT1B;   float* t2b = Fb + aT2B;
  float* out2 = Fb + aOUT2;  float* Z2  = Fb + aZ2;
  float* VfR  = Fb + aVFR;   float* t1R = Fb + aT1R;  float* t2R= Fb + aT2R;
  float* outR = Fb + aOUTR;  float* ZR  = Fb + aZR;
  float* pool = Fb + aPOOL;  float* fc1o= Fb + aFC1O; float* fc2o=Fb + aFC2O;
  float* mpp  = Fb + aMPP;   float* M1p = Fb + aM1P;  float* M2p = Fb + aM2P;
  int* cols1 = Ib + iCOLS1; int* cnt1 = Ib + iCNT1;
  int* cols2 = Ib + iCOLS2; int* cnt2 = Ib + iCNT2;
  ushort* out1h = Ub + uOUT1H; ushort* out1l = Ub + uOUT1L;
  ushort* out1r = Ub + uOUT1R;
  ushort* t1bh  = Ub + uT1BH;  ushort* t1bl  = Ub + uT1BL;
  ushort* t2bh  = Ub + uT2BH;  ushort* t2bl  = Ub + uT2BL;
  ushort* w2t   = Ub + uW2T;
  ushort* vfrh  = Ub + uVFRH;  ushort* vfrl  = Ub + uVFRL;
  ushort* t1rh  = Ub + uT1RH;  ushort* t1rl  = Ub + uT1RL;
  ushort* t2rh  = Ub + uT2RH;  ushort* t2rl  = Ub + uT2RL;
  ushort* wrt   = Ub + uWRT;
  ushort* out1t = Ub + uOUT1T; ushort* z1t   = Ub + uZ1T;
  ushort* out2t = Ub + uOUT2T; ushort* z2t   = Ub + uZ2T;
  ushort* outrt = Ub + uOUTRT; ushort* zrt   = Ub + uZRT;
  ushort* out2b = Ub + uOUT2B; ushort* Gb16  = Ub + uG;

  hipMemsetAsync(out + 640, 0, 9*sizeof(float), stream);

  // ---- graph 1 (x, FIN=6) ----
  xx6_kernel<<<dim3(128),dim3(256),0,stream>>>(x, xx1);
  knn1_kernel<<<dim3(8192),dim3(256),0,stream>>>(x, xx1, cols1, vals1, cnt1, dis1);
  spmm6_kernel<<<dim3(128),dim3(256),0,stream>>>(x, x, t1a, cols1, vals1, cnt1, dis1, 1.f, 0.f, 1.f);
  spmm6_kernel<<<dim3(128),dim3(256),0,stream>>>(t1a, x, t2a, cols1, vals1, cnt1, dis1, 2.f, -1.f, 2.f);
  conv1_kernel<<<dim3(32768),dim3(128),0,stream>>>(x, t1a, t2a, w1, b1, out1, out1h, out1l, out1r);

  // reg1 = ||out1^T (L1 out1)||^2 (single-bf16, split-K partials + reduce)
  spmm_kernel<128,false><<<dim3(32768),dim3(128),0,stream>>>(out1, out1, Z1, nullptr, nullptr,
      cols1, vals1, cnt1, dis1, 1.f, 0.f, 1.f);
  tpack_kernel<false><<<dim3(4,64,16),dim3(256),0,stream>>>(out1, out1t, nullptr, 2048,128, 2048L*128, 128L*2048);
  tpack_kernel<false><<<dim3(4,64,16),dim3(256),0,stream>>>(Z1,   z1t,   nullptr, 2048,128, 2048L*128, 128L*2048);
  mgemm_kernel<false,false,false><<<dim3(1,1,128),dim3(256),0,stream>>>(
      out1t,nullptr,nullptr, nullptr,nullptr,nullptr, z1t, nullptr, M1p,
      nullptr, nullptr, 128,128,2048, 128L*2048, 128L*2048, 128L*128, 256, 16L*128*128);
  redssq_kernel<<<dim3(512),dim3(256),0,stream>>>(M1p, 16L*128*128, 8, 16L*128*128, out+640);
  reeb_pool_kernel<<<dim3(1024),dim3(128),0,stream>>>(out1, sccs, VfR, vfrh, vfrl);

  // ---- graph 2: full dense bf16 Gram (L3-resident) + one knn2 ----
  rownorm_kernel<<<dim3(8192),dim3(256),0,stream>>>(out1, xx2);
  mgemm_kernel<false,false,false><<<dim3(16,16,16),dim3(256),0,stream>>>(
      out1r,nullptr,nullptr, nullptr,nullptr,nullptr, out1r, nullptr, nullptr,
      Gb16, nullptr, 2048,2048,128, (long)NP*128, (long)NP*128, (long)NP*NP, 0, 0);
  knn2_kernel<<<dim3(8192),dim3(256),0,stream>>>(Gb16, xx2, cols2, vals2, cnt2, dis2);

  spmm_kernel<128,true><<<dim3(32768),dim3(128),0,stream>>>(out1, out1, t1b, t1bh, t1bl,
      cols2, vals2, cnt2, dis2, 1.f, 0.f, 1.f);
  spmm_kernel<128,true><<<dim3(32768),dim3(128),0,stream>>>(t1b, out1, t2b, t2bh, t2bl,
      cols2, vals2, cnt2, dis2, 2.f, -1.f, 2.f);
  tpack_kernel<false><<<dim3(16,12,1),dim3(256),0,stream>>>(w2, w2t, nullptr, 384,512, 0,0);
  mgemm_kernel<true,true,true><<<dim3(256,4,1),dim3(256),0,stream>>>(
      out1h,t1bh,t2bh, out1l,t1bl,t2bl, w2t, b2, out2,
      out2b, nullptr, 32768,512,384, 0,0,0, 0, 0);
  // reg2 (split-K x4 partials + bounded-block reduce)
  spmmb_kernel<<<dim3(8192),dim3(256),0,stream>>>(out2, out2b, Z2, cols2, vals2, cnt2, dis2);
  tpack_kernel<false><<<dim3(16,64,16),dim3(256),0,stream>>>(out2, out2t, nullptr, 2048,512, 2048L*512, 512L*2048);
  tpack_kernel<false><<<dim3(16,64,16),dim3(256),0,stream>>>(Z2,   z2t,   nullptr, 2048,512, 2048L*512, 512L*2048);
  mgemm_kernel<false,false,false><<<dim3(4,4,64),dim3(256),0,stream>>>(
      out2t,nullptr,nullptr, nullptr,nullptr,nullptr, z2t, nullptr, M2p,
      nullptr, nullptr, 512,512,2048, 512L*2048, 512L*2048, 512L*512, 512, 16L*512*512);
  redssq_kernel<<<dim3(512),dim3(256),0,stream>>>(M2p, 16L*512*512, 4, 16L*512*512, out+641);

  // ---- Reeb branch ----
  reeb_mm_kernel<128,true><<<dim3(1024),dim3(128),0,stream>>>(lapR, VfR, VfR, t1R, t1rh, t1rl, 1.f, 0.f);
  reeb_mm_kernel<128,true><<<dim3(1024),dim3(128),0,stream>>>(lapR, t1R, VfR, t2R, t2rh, t2rl, 2.f, -1.f);
  tpack_kernel<false><<<dim3(16,12,1),dim3(256),0,stream>>>(wR, wrt, nullptr, 384,512, 0,0);
  mgemm_kernel<true,true,true><<<dim3(8,4,1),dim3(256),0,stream>>>(
      vfrh,t1rh,t2rh, vfrl,t1rl,t2rl, wrt, bRb, outR,
      nullptr, nullptr, 1024,512,384, 0,0,0, 0, 0);
  reeb_mm_kernel<512,false><<<dim3(1024),dim3(256),0,stream>>>(lapR, outR, outR, ZR, nullptr, nullptr, 1.f, 0.f);
  tpack_kernel<false><<<dim3(16,2,16),dim3(256),0,stream>>>(outR, outrt, nullptr, 64,512, 64L*512, 512L*64);
  tpack_kernel<false><<<dim3(16,2,16),dim3(256),0,stream>>>(ZR,   zrt,   nullptr, 64,512, 64L*512, 512L*64);
  mgemm_kernel<false,false,false><<<dim3(4,4,16),dim3(256),0,stream>>>(
      outrt,nullptr,nullptr, nullptr,nullptr,nullptr, zrt, nullptr, nullptr,
      nullptr, out+642, 512,512,64, 512L*64, 512L*64, 0, 0, 0);

  // ---- head ----
  maxpool1_kernel<<<dim3(16,8),dim3(512),0,stream>>>(out2, mpp);
  maxpool2_kernel<<<dim3(16),dim3(512),0,stream>>>(mpp, outR, pool);
  fc_kernel<true ><<<dim3(16,8),dim3(256),0,stream>>>(pool, fw1, fb1, fc1o, 1024, 512);
  fc_kernel<true ><<<dim3(16,2),dim3(256),0,stream>>>(fc1o, fw2, fb2, fc2o, 512, 128);
  fc_kernel<false><<<dim3(16,1),dim3(256),0,stream>>>(fc2o, fw3, fb3, out, 128, 40);
  wreg_kernel<<<dim3(1),dim3(256),0,stream>>>(fw1, fb1, fw2, fb2, fw3, fb3, out+640);
}